// Round 3
// baseline (224.170 us; speedup 1.0000x reference)
//
#include <hip/hip_runtime.h>

#define Cc 64
#define Dd 128
#define Nn 32
#define Kk 4
#define Rr 4
#define Bb 2
#define Hh 48
#define Ww 48
#define Ll 2304
#define EPSf 1e-5f
#define LCc 144   // scan chunk length = L/16

#if __has_builtin(__builtin_amdgcn_exp2f)
#define EXP2F __builtin_amdgcn_exp2f
#else
#define EXP2F exp2f
#endif

__device__ __forceinline__ float wsum64(float v) {
  v += __shfl_xor(v, 32);
  v += __shfl_xor(v, 16);
  v += __shfl_xor(v, 8);
  v += __shfl_xor(v, 4);
  v += __shfl_xor(v, 2);
  v += __shfl_xor(v, 1);
  return v;
}

// max over the 32 lanes of a half-wave (masks stay within the half)
__device__ __forceinline__ float hmax32(float v) {
  v = fmaxf(v, __shfl_xor(v, 1));
  v = fmaxf(v, __shfl_xor(v, 2));
  v = fmaxf(v, __shfl_xor(v, 4));
  v = fmaxf(v, __shfl_xor(v, 8));
  v = fmaxf(v, __shfl_xor(v, 16));
  return v;
}

// ---------------- K1: pre-LN (over C) + in_proj (C -> 2D), split x/z ----------------
__global__ __launch_bounds__(256) void k1_ln_inproj(
    const float* __restrict__ x, const float* __restrict__ g,
    const float* __restrict__ bta, const float* __restrict__ Wp,
    float* __restrict__ xin, float* __restrict__ zb)
{
  __shared__ float xS[16][65];
  __shared__ float xnS[16][64];
  __shared__ float xaS[128][17];
  const int tid = threadIdx.x;
  const int wv = tid >> 6, lane = tid & 63;
  const int pbase = blockIdx.x * 16;       // 4608 pixels total, no b-straddle
  const int b = pbase / Ll;
  const int lbase = pbase % Ll;
  {  // coalesced staging: thread -> (c, 4 consecutive l)
    const int c = tid >> 2, li0 = (tid & 3) * 4;
    const float4 v4 = *(const float4*)&x[(b * Cc + c) * Ll + lbase + li0];
    xS[li0 + 0][c] = v4.x;
    xS[li0 + 1][c] = v4.y;
    xS[li0 + 2][c] = v4.z;
    xS[li0 + 3][c] = v4.w;
  }
  __syncthreads();
  const float gv = g[lane], bv = bta[lane];
  for (int pi = 0; pi < 4; ++pi) {
    const int p = wv * 4 + pi;
    const float v = xS[p][lane];
    const float mu = wsum64(v) * (1.0f / 64.0f);
    const float dv = v - mu;
    const float var = wsum64(dv * dv) * (1.0f / 64.0f);
    const float rs = rsqrtf(var + EPSf);
    xnS[p][lane] = dv * rs * gv + bv;
  }
  __syncthreads();
  float acc[4][4];
  #pragma unroll
  for (int pi = 0; pi < 4; ++pi)
    #pragma unroll
    for (int m = 0; m < 4; ++m) acc[pi][m] = 0.f;
  const float4* W4 = (const float4*)Wp;
  #pragma unroll 4
  for (int c4 = 0; c4 < 16; ++c4) {
    float4 xn4[4];
    #pragma unroll
    for (int pi = 0; pi < 4; ++pi)
      xn4[pi] = ((const float4*)xnS[wv * 4 + pi])[c4];
    #pragma unroll
    for (int m = 0; m < 4; ++m) {
      const float4 w4 = W4[(lane + 64 * m) * 16 + c4];
      #pragma unroll
      for (int pi = 0; pi < 4; ++pi)
        acc[pi][m] += xn4[pi].x * w4.x + xn4[pi].y * w4.y +
                      xn4[pi].z * w4.z + xn4[pi].w * w4.w;
    }
  }
  #pragma unroll
  for (int pi = 0; pi < 4; ++pi) {
    const int l = lbase + wv * 4 + pi;
    zb[(b * Ll + l) * Dd + lane]      = acc[pi][2];
    zb[(b * Ll + l) * Dd + lane + 64] = acc[pi][3];
    xaS[lane][wv * 4 + pi]      = acc[pi][0];
    xaS[lane + 64][wv * 4 + pi] = acc[pi][1];
  }
  __syncthreads();
  const int d = tid >> 1, off = (tid & 1) * 8;
  float* dst = &xin[(b * Dd + d) * Ll + lbase + off];
  #pragma unroll
  for (int i = 0; i < 8; ++i) dst[i] = xaS[d][off + i];
}

// ---------------- K3: conv3x3+SiLU (fused) + projections -> xc, {delta,delta*u}, {B,C} ----------------
// B,C written INTERLEAVED: BCm float layout (b,k,l,n,{B,C}) -> k4 lane n loads one
// dwordx2 per position (256B/position wave footprint, fully coalesced).
__global__ __launch_bounds__(512) void k3_proj(
    const float* __restrict__ xin, const float* __restrict__ cw,
    const float* __restrict__ cb, const float* __restrict__ xpw,
    const float* __restrict__ dtw, const float* __restrict__ dtb,
    float* __restrict__ xc, float2* __restrict__ dd2,
    float* __restrict__ BCm)
{
  __shared__ float xinS[128][30];
  __shared__ float xvS[8][132];
  __shared__ float dtsS[8][16];
  const int t = threadIdx.x;
  const int pb = blockIdx.x * 8;
  const int b = pb / Ll;
  const int lb = pb % Ll;
  const int h0 = lb / Ww, w0 = lb % Ww;
  // stage 3 rows x 10 cols x 128 d of xin, zero-padded at image borders
  for (int i = t; i < 3840; i += 512) {
    const int d = i / 30, j = i % 30;
    const int r = j / 10, c = j % 10;
    const int hh = h0 + r - 1, ww = w0 + c - 1;
    float v = 0.f;
    if (hh >= 0 && hh < Hh && ww >= 0 && ww < Ww)
      v = xin[(b * Dd + d) * Ll + hh * Ww + ww];
    xinS[d][j] = v;
  }
  __syncthreads();
  // depthwise conv + bias + SiLU -> xvS (pixel-major for the GEMM below)
  for (int i = t; i < 1024; i += 512) {
    const int pi = i >> 7, d = i & 127;
    float acc = cb[d];
    #pragma unroll
    for (int r = 0; r < 3; ++r)
      #pragma unroll
      for (int c = 0; c < 3; ++c)
        acc += xinS[d][r * 10 + pi + c] * cw[d * 9 + r * 3 + c];
    const float sig = 1.0f / (1.0f + __expf(-acc));
    xvS[pi][d] = acc * sig;
  }
  __syncthreads();
  if (t < 272) {   // projection GEMM: 4 k x 68 c rows, 8 px each
    const int k = t / 68, c = t % 68;
    const size_t bkL = (size_t)(b * Kk + k) * Ll;
    float acc[8];
    #pragma unroll
    for (int pi = 0; pi < 8; ++pi) acc[pi] = 0.f;
    const float4* w4p = (const float4*)(xpw + (k * 68 + c) * 128);
    for (int d4 = 0; d4 < 32; ++d4) {
      const float4 w4 = w4p[d4];
      #pragma unroll
      for (int pi = 0; pi < 8; ++pi) {
        const float4 x4 = ((const float4*)xvS[pi])[d4];
        acc[pi] += x4.x * w4.x + x4.y * w4.y + x4.z * w4.z + x4.w * w4.w;
      }
    }
    #pragma unroll
    for (int pi = 0; pi < 8; ++pi) {
      const int l0 = lb + pi;
      const int h = l0 / Ww, w = l0 % Ww;
      int lk;
      if      (k == 0) lk = l0;
      else if (k == 1) lk = w * Hh + h;
      else if (k == 2) lk = Ll - 1 - l0;
      else             lk = Ll - 1 - (w * Hh + h);
      if (c < Rr)
        dtsS[pi][k * 4 + c] = acc[pi];
      else if (c < Rr + Nn)
        BCm[((bkL + lk) * Nn + (c - Rr)) * 2]     = acc[pi];
      else
        BCm[((bkL + lk) * Nn + (c - Rr - Nn)) * 2 + 1] = acc[pi];
    }
  } else {   // idle-during-proj threads handle the xc write (for k5's Ds-term)
    for (int i = t - 272; i < 1024; i += 240) {
      const int d = i >> 3, pi = i & 7;
      xc[(b * Dd + d) * Ll + lb + pi] = xvS[pi][d];
    }
  }
  __syncthreads();
  {  // delta + softplus + pack {delta, delta*u}
    const int k = t >> 7, dd = t & 127;
    const float4 dw = *(const float4*)&dtw[(k * Dd + dd) * 4];
    const float biasv = dtb[k * Dd + dd];
    float2* drow = dd2 + ((size_t)((b * Kk + k) * Dd) + dd) * Ll;
    float2 buf[8];
    #pragma unroll
    for (int pi = 0; pi < 8; ++pi) {
      const float a = biasv
          + dtsS[pi][k * 4 + 0] * dw.x + dtsS[pi][k * 4 + 1] * dw.y
          + dtsS[pi][k * 4 + 2] * dw.z + dtsS[pi][k * 4 + 3] * dw.w;
      const float sp = (a > 20.f) ? a : log1pf(__expf(a));
      buf[pi] = make_float2(sp, sp * xvS[pi][dd]);
    }
    if (k == 0) {
      float4* f4 = (float4*)(drow + lb);
      #pragma unroll
      for (int j = 0; j < 4; ++j)
        f4[j] = make_float4(buf[2 * j].x, buf[2 * j].y, buf[2 * j + 1].x, buf[2 * j + 1].y);
    } else if (k == 2) {
      float4* f4 = (float4*)(drow + (Ll - 8 - lb));
      #pragma unroll
      for (int j = 0; j < 4; ++j)
        f4[j] = make_float4(buf[7 - 2 * j].x, buf[7 - 2 * j].y, buf[6 - 2 * j].x, buf[6 - 2 * j].y);
    } else {
      #pragma unroll
      for (int pi = 0; pi < 8; ++pi) {
        const int l0 = lb + pi;
        const int h = l0 / Ww, w = l0 % Ww;
        int lk = w * Hh + h;
        if (k == 3) lk = Ll - 1 - lk;
        drow[lk] = buf[pi];
      }
    }
  }
}

// ---------------- K4: single-pass scan + TILED truncated carry correction ----------------
// Pass 1: local scan (carry=0) writes y_local, records hend/sumD/max|c|; B,C come in
// as one float2 per (position, n). Serial combine gives exact carries. Correction adds
//   y_t += sum_n carry_n * exp(A_n * P_t) * c_t[n]
// tiled like pass 1, stopping at tile granularity once the rigorous bound
// 32*max|carry|*max|c|*2^(AmaxE*P) < 1e-5 holds (P = in-chunk delta prefix, >0).
// block index = (d<<3)|(b*4+k): %8 XCD round-robin keeps one (b,k)'s BC/dd2 slice
// L2-resident per XCD.
__global__ __launch_bounds__(512) void k4_scan(
    const float2* __restrict__ dd2, const float* __restrict__ BCm,
    const float* __restrict__ Alogs, float* __restrict__ ys)
{
  __shared__ float hendS[16][32];
  __shared__ float carryS[16][32];
  __shared__ float sumDS[16];
  __shared__ float cmaxS[16];
  __shared__ float pS[16][8][36];
  const int tid = threadIdx.x;
  const int s = tid >> 5, n = tid & 31;
  const int blk = blockIdx.x;
  const int bk = blk & 7;          // (b,k) -> XCD
  const int d = blk >> 3;
  const int b = bk >> 2, k = bk & 3;
  const float An = -__expf(Alogs[(k * Dd + d) * Nn + n]);
  const float AnE = An * 1.44269504f;
  const size_t bkL = (size_t)(b * Kk + k) * Ll;
  const float2* dP = dd2 + ((size_t)((b * Kk + k) * Dd) + d) * Ll;
  const float2* bcP = (const float2*)BCm + bkL * Nn + n;  // stride Nn float2/position
  const int lbeg = s * LCc;
  float* yP = ys + ((size_t)((b * Kk + k) * Dd) + d) * Ll + lbeg;
  const int rrow = n & 7, qtr = n >> 3;

  // ---- pass 1: local scan (carry=0), y_local out, hend + sumD + chunk max|c| ----
  float h = 0.f, sumD = 0.f, cmx = 0.f;
  {
    const float4* q4 = (const float4*)(dP + lbeg);
    const float2* bcl = bcP + (size_t)lbeg * Nn;
    float4 qa = q4[0], qb = q4[1];
    float2 bc0 = bcl[0], bc1 = bcl[Nn], bc2 = bcl[2 * Nn], bc3 = bcl[3 * Nn];
    for (int t8 = 0; t8 < LCc / 8; ++t8) {
      #pragma unroll
      for (int half = 0; half < 2; ++half) {
        q4 += 2; bcl += 4 * Nn;   // prefetch next 4 positions (overread guarded by ws layout)
        const float4 qa_n = q4[0], qb_n = q4[1];
        const float2 bc0n = bcl[0], bc1n = bcl[Nn], bc2n = bcl[2 * Nn], bc3n = bcl[3 * Nn];
        h = EXP2F(qa.x * AnE) * h + qa.y * bc0.x; pS[s][half * 4 + 0][n] = h * bc0.y;
        h = EXP2F(qa.z * AnE) * h + qa.w * bc1.x; pS[s][half * 4 + 1][n] = h * bc1.y;
        h = EXP2F(qb.x * AnE) * h + qb.y * bc2.x; pS[s][half * 4 + 2][n] = h * bc2.y;
        h = EXP2F(qb.z * AnE) * h + qb.w * bc3.x; pS[s][half * 4 + 3][n] = h * bc3.y;
        sumD += (qa.x + qa.z) + (qb.x + qb.z);
        cmx = fmaxf(cmx, fmaxf(fmaxf(fabsf(bc0.y), fabsf(bc1.y)),
                               fmaxf(fabsf(bc2.y), fabsf(bc3.y))));
        qa = qa_n; qb = qb_n; bc0 = bc0n; bc1 = bc1n; bc2 = bc2n; bc3 = bc3n;
      }
      // reduce the 8-step tile: lane sums a quarter-row, 2 shuffles combine
      const float4 a4 = *(const float4*)&pS[s][rrow][qtr * 8];
      const float4 d4v = *(const float4*)&pS[s][rrow][qtr * 8 + 4];
      float sum = ((a4.x + a4.y) + (a4.z + a4.w)) + ((d4v.x + d4v.y) + (d4v.z + d4v.w));
      sum += __shfl_xor(sum, 8);
      sum += __shfl_xor(sum, 16);
      if (n < 8) yP[t8 * 8 + n] = sum;
    }
  }
  hendS[s][n] = h;
  const float cmxAll = hmax32(cmx);
  if (n == 0) { sumDS[s] = sumD; cmaxS[s] = cmxAll; }
  __syncthreads();
  // ---- exact serial carry combine over 16 chunks (half-wave) ----
  if (tid < 32) {
    float carry = 0.f;
    #pragma unroll
    for (int s2 = 0; s2 < 16; ++s2) {
      carryS[s2][tid] = carry;
      carry = EXP2F(AnE * sumDS[s2]) * carry + hendS[s2][tid];
    }
  }
  __syncthreads();
  // ---- truncated carry correction, tiled like pass 1 ----
  const float carry = carryS[s][n];
  const float mc = hmax32(fabsf(carry));
  const float AmaxE = hmax32(AnE);               // all < 0; max = slowest decay
  // smallest P with 32*mc*cmax*2^(AmaxE*P) <= 1e-5  (log2f(0) = -inf => skip)
  const float Pstop = log2f(mc * cmaxS[s] * 3.2e6f) / (-AmaxE);
  {
    float hc = carry, P = 0.f;
    const float4* q4 = (const float4*)(dP + lbeg);
    const float2* cl = bcP + (size_t)lbeg * Nn;
    for (int t8 = 0; t8 < LCc / 8; ++t8) {
      if (!(P < Pstop)) break;                   // uniform per half-wave
      #pragma unroll
      for (int half = 0; half < 2; ++half) {
        const float4 qa = q4[0], qb = q4[1];
        q4 += 2;
        hc *= EXP2F(qa.x * AnE); pS[s][half * 4 + 0][n] = hc * cl[0].y;
        hc *= EXP2F(qa.z * AnE); pS[s][half * 4 + 1][n] = hc * cl[Nn].y;
        hc *= EXP2F(qb.x * AnE); pS[s][half * 4 + 2][n] = hc * cl[2 * Nn].y;
        hc *= EXP2F(qb.z * AnE); pS[s][half * 4 + 3][n] = hc * cl[3 * Nn].y;
        P += (qa.x + qa.z) + (qb.x + qb.z);
        cl += 4 * Nn;
      }
      const float4 a4 = *(const float4*)&pS[s][rrow][qtr * 8];
      const float4 d4v = *(const float4*)&pS[s][rrow][qtr * 8 + 4];
      float sum = ((a4.x + a4.y) + (a4.z + a4.w)) + ((d4v.x + d4v.y) + (d4v.z + d4v.w));
      sum += __shfl_xor(sum, 8);
      sum += __shfl_xor(sum, 16);
      if (n < 8) yP[t8 * 8 + n] += sum;
    }
  }
}

// ---------------- K5: merge + Ds-term + out-LN + SiLU(z)* + out_proj + residual ----------------
// Block = one 4x4 pixel tile: ALL four scan directions stage as float4 loads
// (dir0/2 contiguous along w, dir1/3 contiguous along h).
__global__ __launch_bounds__(256) void k5_merge(
    const float* __restrict__ ys, const float* __restrict__ zb,
    const float* __restrict__ og, const float* __restrict__ ob,
    const float* __restrict__ Wo, const float* __restrict__ resid,
    const float* __restrict__ xc, const float* __restrict__ DsP,
    float* __restrict__ out)
{
  __shared__ float ysS[4][16][128];
  __shared__ float tS[16][128];
  __shared__ float oS[64][17];
  __shared__ float xcS[16][128];
  const int tid = threadIdx.x;
  const int wv = tid >> 6, lane = tid & 63;
  const int tb = blockIdx.x;           // 288 tiles = 2 b x 12 x 12
  const int b = tb / 144;
  const int ti = tb % 144;
  const int tr = ti / 12, tc = ti % 12;
  const int h0 = tr * 4, w0 = tc * 4;
  {  // stage xc + 4 direction tiles; p = i*4+j (i = row in tile, j = col)
    const int dch = tid & 127, half = tid >> 7;   // 2 threads per channel
    #pragma unroll
    for (int ii = 0; ii < 2; ++ii) {
      const int i = half * 2 + ii;
      const int l0 = (h0 + i) * Ww + w0;
      float4 v;
      v = *(const float4*)&xc[(b * Dd + dch) * Ll + l0];
      xcS[i * 4 + 0][dch] = v.x; xcS[i * 4 + 1][dch] = v.y;
      xcS[i * 4 + 2][dch] = v.z; xcS[i * 4 + 3][dch] = v.w;
      v = *(const float4*)&ys[((size_t)(b * Kk + 0) * Dd + dch) * Ll + l0];
      ysS[0][i * 4 + 0][dch] = v.x; ysS[0][i * 4 + 1][dch] = v.y;
      ysS[0][i * 4 + 2][dch] = v.z; ysS[0][i * 4 + 3][dch] = v.w;
      const int r2 = Ll - 4 - (h0 + i) * Ww - w0;   // dir2: l = Ll-1-l0, reversed
      v = *(const float4*)&ys[((size_t)(b * Kk + 2) * Dd + dch) * Ll + r2];
      ysS[2][i * 4 + 3][dch] = v.x; ysS[2][i * 4 + 2][dch] = v.y;
      ysS[2][i * 4 + 1][dch] = v.z; ysS[2][i * 4 + 0][dch] = v.w;
    }
    #pragma unroll
    for (int jj = 0; jj < 2; ++jj) {
      const int j = half * 2 + jj;
      const int l1 = (w0 + j) * Hh + h0;            // dir1: col-major, i contiguous
      float4 v = *(const float4*)&ys[((size_t)(b * Kk + 1) * Dd + dch) * Ll + l1];
      ysS[1][0 * 4 + j][dch] = v.x; ysS[1][1 * 4 + j][dch] = v.y;
      ysS[1][2 * 4 + j][dch] = v.z; ysS[1][3 * 4 + j][dch] = v.w;
      const int r3 = Ll - 4 - (w0 + j) * Hh - h0;   // dir3: l = Ll-1-l1, reversed
      v = *(const float4*)&ys[((size_t)(b * Kk + 3) * Dd + dch) * Ll + r3];
      ysS[3][3 * 4 + j][dch] = v.x; ysS[3][2 * 4 + j][dch] = v.y;
      ysS[3][1 * 4 + j][dch] = v.z; ysS[3][0 * 4 + j][dch] = v.w;
    }
  }
  float sDs[2];
  #pragma unroll
  for (int m = 0; m < 2; ++m) {
    const int dch = lane + 64 * m;
    sDs[m] = DsP[dch] + DsP[Dd + dch] + DsP[2 * Dd + dch] + DsP[3 * Dd + dch];
  }
  __syncthreads();
  for (int pi = 0; pi < 4; ++pi) {
    const int p = wv * 4 + pi;
    const int l0 = (h0 + (p >> 2)) * Ww + w0 + (p & 3);
    float tv[2];
    #pragma unroll
    for (int m = 0; m < 2; ++m) {
      const int dch = lane + 64 * m;
      tv[m] = ysS[0][p][dch] + ysS[1][p][dch] + ysS[2][p][dch] + ysS[3][p][dch]
            + sDs[m] * xcS[p][dch];
    }
    const float mu = wsum64(tv[0] + tv[1]) * (1.0f / 128.0f);
    const float q = wsum64((tv[0] - mu) * (tv[0] - mu) +
                           (tv[1] - mu) * (tv[1] - mu)) * (1.0f / 128.0f);
    const float rs = rsqrtf(q + EPSf);
    #pragma unroll
    for (int m = 0; m < 2; ++m) {
      const int dch = lane + 64 * m;
      const float zz = zb[(size_t)(b * Ll + l0) * Dd + dch];
      const float sig = 1.0f / (1.0f + __expf(-zz));
      tS[p][dch] = ((tv[m] - mu) * rs * og[dch] + ob[dch]) * (zz * sig);
    }
  }
  __syncthreads();
  float acc[4] = {0.f, 0.f, 0.f, 0.f};
  const float4* W4 = (const float4*)Wo;     // out_proj_w (64,128)
  for (int d4 = 0; d4 < 32; ++d4) {
    const float4 w4 = W4[lane * 32 + d4];
    #pragma unroll
    for (int pi = 0; pi < 4; ++pi) {
      const float4 t4 = ((const float4*)tS[wv * 4 + pi])[d4];
      acc[pi] += t4.x * w4.x + t4.y * w4.y + t4.z * w4.z + t4.w * w4.w;
    }
  }
  #pragma unroll
  for (int pi = 0; pi < 4; ++pi) oS[lane][wv * 4 + pi] = acc[pi];
  __syncthreads();
  const int c = tid >> 2, q = tid & 3;     // c = out channel, q = tile row
  const size_t obase = (size_t)(b * Cc + c) * Ll + (size_t)(h0 + q) * Ww + w0;
  const float4 r4 = *(const float4*)(resid + obase);
  float4 o4;
  o4.x = oS[c][q * 4 + 0] + r4.x;
  o4.y = oS[c][q * 4 + 1] + r4.y;
  o4.z = oS[c][q * 4 + 2] + r4.z;
  o4.w = oS[c][q * 4 + 3] + r4.w;
  *(float4*)(out + obase) = o4;
}

extern "C" void kernel_launch(void* const* d_in, const int* in_sizes, int n_in,
                              void* d_out, int out_size, void* d_ws, size_t ws_size,
                              hipStream_t stream)
{
  (void)in_sizes; (void)n_in; (void)out_size; (void)ws_size;
  const float* fufea1     = (const float*)d_in[0];
  const float* ln_g       = (const float*)d_in[1];
  const float* ln_b       = (const float*)d_in[2];
  const float* in_proj_w  = (const float*)d_in[3];
  const float* conv_w     = (const float*)d_in[4];
  const float* conv_b     = (const float*)d_in[5];
  const float* x_proj_w   = (const float*)d_in[6];
  const float* dt_w       = (const float*)d_in[7];
  const float* dt_b       = (const float*)d_in[8];
  const float* A_logs     = (const float*)d_in[9];
  const float* Ds         = (const float*)d_in[10];
  const float* out_ln_g   = (const float*)d_in[11];
  const float* out_ln_b   = (const float*)d_in[12];
  const float* out_proj_w = (const float*)d_in[13];

  float* ws = (float*)d_ws;
  // k4's 1-deep prefetch overreads ~1KB past dd2/BCm row ends -> keep a live
  // buffer after each (dd2 -> BCm -> zb; loads only, within ws allocation).
  float2* dd2 = (float2*)ws;        // (B,K,D,L) float2   4718592 floats
  float* BCm  = ws + 4718592;       // (B,K,L,N,{B,C})    1179648
  float* zb   = ws + 5898240;       // (B,L,D)             589824
  float* xc   = ws + 6488064;       // (B,D,L)             589824
  float* ysb  = ws + 7077888;       // (B,K,D,L)          2359296
  float* xin  = ws + 7077888;       // (B,D,L) — overlaps ysb (dead before k4)
  // total: 9437184 floats = 37.75 MB

  k1_ln_inproj<<<288, 256, 0, stream>>>(fufea1, ln_g, ln_b, in_proj_w, xin, zb);
  k3_proj<<<576, 512, 0, stream>>>(xin, conv_w, conv_b, x_proj_w, dt_w, dt_b,
                                   xc, dd2, BCm);
  k4_scan<<<1024, 512, 0, stream>>>(dd2, BCm, A_logs, ysb);
  k5_merge<<<288, 256, 0, stream>>>(ysb, zb, out_ln_g, out_ln_b, out_proj_w, fufea1,
                                    xc, Ds, (float*)d_out);
}

// Round 4
// 207.956 us; speedup vs baseline: 1.0780x; 1.0780x over previous
//
#include <hip/hip_runtime.h>

#define Cc 64
#define Dd 128
#define Nn 32
#define Kk 4
#define Rr 4
#define Bb 2
#define Hh 48
#define Ww 48
#define Ll 2304
#define EPSf 1e-5f
#define LCc 144   // scan chunk length = L/16

#if __has_builtin(__builtin_amdgcn_exp2f)
#define EXP2F __builtin_amdgcn_exp2f
#else
#define EXP2F exp2f
#endif

__device__ __forceinline__ float wsum64(float v) {
  v += __shfl_xor(v, 32);
  v += __shfl_xor(v, 16);
  v += __shfl_xor(v, 8);
  v += __shfl_xor(v, 4);
  v += __shfl_xor(v, 2);
  v += __shfl_xor(v, 1);
  return v;
}

// max over the 32 lanes of a half-wave (masks stay within the half)
__device__ __forceinline__ float hmax32(float v) {
  v = fmaxf(v, __shfl_xor(v, 1));
  v = fmaxf(v, __shfl_xor(v, 2));
  v = fmaxf(v, __shfl_xor(v, 4));
  v = fmaxf(v, __shfl_xor(v, 8));
  v = fmaxf(v, __shfl_xor(v, 16));
  return v;
}

// ---------------- K1: pre-LN (over C) + in_proj (C -> 2D), split x/z ----------------
__global__ __launch_bounds__(256) void k1_ln_inproj(
    const float* __restrict__ x, const float* __restrict__ g,
    const float* __restrict__ bta, const float* __restrict__ Wp,
    float* __restrict__ xin, float* __restrict__ zb)
{
  __shared__ float xS[16][65];
  __shared__ float xnS[16][64];
  __shared__ float xaS[128][17];
  const int tid = threadIdx.x;
  const int wv = tid >> 6, lane = tid & 63;
  const int pbase = blockIdx.x * 16;       // 4608 pixels total, no b-straddle
  const int b = pbase / Ll;
  const int lbase = pbase % Ll;
  {  // coalesced staging: thread -> (c, 4 consecutive l)
    const int c = tid >> 2, li0 = (tid & 3) * 4;
    const float4 v4 = *(const float4*)&x[(b * Cc + c) * Ll + lbase + li0];
    xS[li0 + 0][c] = v4.x;
    xS[li0 + 1][c] = v4.y;
    xS[li0 + 2][c] = v4.z;
    xS[li0 + 3][c] = v4.w;
  }
  __syncthreads();
  const float gv = g[lane], bv = bta[lane];
  for (int pi = 0; pi < 4; ++pi) {
    const int p = wv * 4 + pi;
    const float v = xS[p][lane];
    const float mu = wsum64(v) * (1.0f / 64.0f);
    const float dv = v - mu;
    const float var = wsum64(dv * dv) * (1.0f / 64.0f);
    const float rs = rsqrtf(var + EPSf);
    xnS[p][lane] = dv * rs * gv + bv;
  }
  __syncthreads();
  float acc[4][4];
  #pragma unroll
  for (int pi = 0; pi < 4; ++pi)
    #pragma unroll
    for (int m = 0; m < 4; ++m) acc[pi][m] = 0.f;
  const float4* W4 = (const float4*)Wp;
  #pragma unroll 4
  for (int c4 = 0; c4 < 16; ++c4) {
    float4 xn4[4];
    #pragma unroll
    for (int pi = 0; pi < 4; ++pi)
      xn4[pi] = ((const float4*)xnS[wv * 4 + pi])[c4];
    #pragma unroll
    for (int m = 0; m < 4; ++m) {
      const float4 w4 = W4[(lane + 64 * m) * 16 + c4];
      #pragma unroll
      for (int pi = 0; pi < 4; ++pi)
        acc[pi][m] += xn4[pi].x * w4.x + xn4[pi].y * w4.y +
                      xn4[pi].z * w4.z + xn4[pi].w * w4.w;
    }
  }
  #pragma unroll
  for (int pi = 0; pi < 4; ++pi) {
    const int l = lbase + wv * 4 + pi;
    zb[(b * Ll + l) * Dd + lane]      = acc[pi][2];
    zb[(b * Ll + l) * Dd + lane + 64] = acc[pi][3];
    xaS[lane][wv * 4 + pi]      = acc[pi][0];
    xaS[lane + 64][wv * 4 + pi] = acc[pi][1];
  }
  __syncthreads();
  const int d = tid >> 1, off = (tid & 1) * 8;
  float* dst = &xin[(b * Dd + d) * Ll + lbase + off];
  #pragma unroll
  for (int i = 0; i < 8; ++i) dst[i] = xaS[d][off + i];
}

// ---------------- K3: conv3x3+SiLU (fused) + projections -> xc, {delta,delta*u}, B, C ----------------
// Bm/Cm in the COALESCED (b,k,l,n) layout (measured best: r2 = 53.9us k4).
__global__ __launch_bounds__(512) void k3_proj(
    const float* __restrict__ xin, const float* __restrict__ cw,
    const float* __restrict__ cb, const float* __restrict__ xpw,
    const float* __restrict__ dtw, const float* __restrict__ dtb,
    float* __restrict__ xc, float2* __restrict__ dd2,
    float* __restrict__ Bm, float* __restrict__ Cm)
{
  __shared__ float xinS[128][30];
  __shared__ float xvS[8][132];
  __shared__ float dtsS[8][16];
  const int t = threadIdx.x;
  const int pb = blockIdx.x * 8;
  const int b = pb / Ll;
  const int lb = pb % Ll;
  const int h0 = lb / Ww, w0 = lb % Ww;
  // stage 3 rows x 10 cols x 128 d of xin, zero-padded at image borders
  for (int i = t; i < 3840; i += 512) {
    const int d = i / 30, j = i % 30;
    const int r = j / 10, c = j % 10;
    const int hh = h0 + r - 1, ww = w0 + c - 1;
    float v = 0.f;
    if (hh >= 0 && hh < Hh && ww >= 0 && ww < Ww)
      v = xin[(b * Dd + d) * Ll + hh * Ww + ww];
    xinS[d][j] = v;
  }
  __syncthreads();
  // depthwise conv + bias + SiLU -> xvS (pixel-major for the GEMM below)
  for (int i = t; i < 1024; i += 512) {
    const int pi = i >> 7, d = i & 127;
    float acc = cb[d];
    #pragma unroll
    for (int r = 0; r < 3; ++r)
      #pragma unroll
      for (int c = 0; c < 3; ++c)
        acc += xinS[d][r * 10 + pi + c] * cw[d * 9 + r * 3 + c];
    const float sig = 1.0f / (1.0f + __expf(-acc));
    xvS[pi][d] = acc * sig;
  }
  __syncthreads();
  if (t < 272) {   // projection GEMM: 4 k x 68 c rows, 8 px each
    const int k = t / 68, c = t % 68;
    const size_t bkL = (size_t)(b * Kk + k) * Ll;
    float acc[8];
    #pragma unroll
    for (int pi = 0; pi < 8; ++pi) acc[pi] = 0.f;
    const float4* w4p = (const float4*)(xpw + (k * 68 + c) * 128);
    for (int d4 = 0; d4 < 32; ++d4) {
      const float4 w4 = w4p[d4];
      #pragma unroll
      for (int pi = 0; pi < 8; ++pi) {
        const float4 x4 = ((const float4*)xvS[pi])[d4];
        acc[pi] += x4.x * w4.x + x4.y * w4.y + x4.z * w4.z + x4.w * w4.w;
      }
    }
    #pragma unroll
    for (int pi = 0; pi < 8; ++pi) {
      const int l0 = lb + pi;
      const int h = l0 / Ww, w = l0 % Ww;
      int lk;
      if      (k == 0) lk = l0;
      else if (k == 1) lk = w * Hh + h;
      else if (k == 2) lk = Ll - 1 - l0;
      else             lk = Ll - 1 - (w * Hh + h);
      if (c < Rr)            dtsS[pi][k * 4 + c] = acc[pi];
      else if (c < Rr + Nn)  Bm[(bkL + lk) * Nn + (c - Rr)] = acc[pi];
      else                   Cm[(bkL + lk) * Nn + (c - Rr - Nn)] = acc[pi];
    }
  } else {   // idle-during-proj threads handle the xc write (for k5's Ds-term)
    for (int i = t - 272; i < 1024; i += 240) {
      const int d = i >> 3, pi = i & 7;
      xc[(b * Dd + d) * Ll + lb + pi] = xvS[pi][d];
    }
  }
  __syncthreads();
  {  // delta + softplus + pack {delta, delta*u}
    const int k = t >> 7, dd = t & 127;
    const float4 dw = *(const float4*)&dtw[(k * Dd + dd) * 4];
    const float biasv = dtb[k * Dd + dd];
    float2* drow = dd2 + ((size_t)((b * Kk + k) * Dd) + dd) * Ll;
    float2 buf[8];
    #pragma unroll
    for (int pi = 0; pi < 8; ++pi) {
      const float a = biasv
          + dtsS[pi][k * 4 + 0] * dw.x + dtsS[pi][k * 4 + 1] * dw.y
          + dtsS[pi][k * 4 + 2] * dw.z + dtsS[pi][k * 4 + 3] * dw.w;
      const float sp = (a > 20.f) ? a : log1pf(__expf(a));
      buf[pi] = make_float2(sp, sp * xvS[pi][dd]);
    }
    if (k == 0) {
      float4* f4 = (float4*)(drow + lb);
      #pragma unroll
      for (int j = 0; j < 4; ++j)
        f4[j] = make_float4(buf[2 * j].x, buf[2 * j].y, buf[2 * j + 1].x, buf[2 * j + 1].y);
    } else if (k == 2) {
      float4* f4 = (float4*)(drow + (Ll - 8 - lb));
      #pragma unroll
      for (int j = 0; j < 4; ++j)
        f4[j] = make_float4(buf[7 - 2 * j].x, buf[7 - 2 * j].y, buf[6 - 2 * j].x, buf[6 - 2 * j].y);
    } else {
      #pragma unroll
      for (int pi = 0; pi < 8; ++pi) {
        const int l0 = lb + pi;
        const int h = l0 / Ww, w = l0 % Ww;
        int lk = w * Hh + h;
        if (k == 3) lk = Ll - 1 - lk;
        drow[lk] = buf[pi];
      }
    }
  }
}

// ---------------- K4: single-pass scan + TILED truncated carry correction ----------------
// Pass 1: local scan (carry=0) writes y_local, records hend/sumD/max|c|.
// 2-slot rotation prefetch: consume slot 'half' via SSA aliases, then load step+2
// directly into the same slot names -> zero rotation movs (static indices), 8-position
// prefetch depth. Serial combine gives exact carries; tiled truncated correction adds
//   y_t += sum_n carry_n * exp(A_n * P_t) * c_t[n]
// stopping once 32*max|carry|*max|c|*2^(AmaxE*P) < 1e-5 (P = in-chunk delta prefix).
// block index = (d<<3)|(b*4+k): %8 XCD round-robin keeps one (b,k)'s B/C/dd2 slice
// L2-resident per XCD.
__global__ __launch_bounds__(512) void k4_scan(
    const float2* __restrict__ dd2, const float* __restrict__ Bm,
    const float* __restrict__ Cm, const float* __restrict__ Alogs,
    float* __restrict__ ys)
{
  __shared__ float hendS[16][32];
  __shared__ float carryS[16][32];
  __shared__ float sumDS[16];
  __shared__ float cmaxS[16];
  __shared__ float pS[16][8][36];
  const int tid = threadIdx.x;
  const int s = tid >> 5, n = tid & 31;
  const int blk = blockIdx.x;
  const int bk = blk & 7;          // (b,k) -> XCD
  const int d = blk >> 3;
  const int b = bk >> 2, k = bk & 3;
  const float An = -__expf(Alogs[(k * Dd + d) * Nn + n]);
  const float AnE = An * 1.44269504f;
  const size_t bkL = (size_t)(b * Kk + k) * Ll;
  const float2* dP = dd2 + ((size_t)((b * Kk + k) * Dd) + d) * Ll;
  const float* bP = Bm + bkL * Nn + n;
  const float* cP = Cm + bkL * Nn + n;
  const int lbeg = s * LCc;
  float* yP = ys + ((size_t)((b * Kk + k) * Dd) + d) * Ll + lbeg;
  const int rrow = n & 7, qtr = n >> 3;

  // ---- pass 1: local scan (carry=0), y_local out, hend + sumD + chunk max|c| ----
  float h = 0.f, sumD = 0.f, cmx = 0.f;
  {
    const float4* q4 = (const float4*)(dP + lbeg);
    const float* bl = bP + (size_t)lbeg * Nn;
    const float* cl = cP + (size_t)lbeg * Nn;
    // 2-slot rotation register file: slot i holds step (2*t8 + i + phase) data
    float4 qa[2], qb[2];
    float bv[2][4], cv[2][4];
    #pragma unroll
    for (int i = 0; i < 2; ++i) {
      qa[i] = q4[2 * i]; qb[i] = q4[2 * i + 1];
      #pragma unroll
      for (int j = 0; j < 4; ++j) {
        bv[i][j] = bl[(4 * i + j) * Nn];
        cv[i][j] = cl[(4 * i + j) * Nn];
      }
    }
    q4 += 4; bl += 8 * Nn; cl += 8 * Nn;   // point at step 2 (prefetch target)
    for (int t8 = 0; t8 < LCc / 8; ++t8) {
      #pragma unroll
      for (int half = 0; half < 2; ++half) {
        // consume slot 'half' via SSA aliases (free)
        const float4 a = qa[half], bq = qb[half];
        const float B0 = bv[half][0], B1 = bv[half][1], B2 = bv[half][2], B3 = bv[half][3];
        const float C0 = cv[half][0], C1 = cv[half][1], C2 = cv[half][2], C3 = cv[half][3];
        // refill slot 'half' with step+2 (pure loads; scheduler hoists to cover latency;
        // overreads <=1KB past row end, guarded by ws layout)
        qa[half] = q4[0]; qb[half] = q4[1];
        bv[half][0] = bl[0]; bv[half][1] = bl[Nn];
        bv[half][2] = bl[2 * Nn]; bv[half][3] = bl[3 * Nn];
        cv[half][0] = cl[0]; cv[half][1] = cl[Nn];
        cv[half][2] = cl[2 * Nn]; cv[half][3] = cl[3 * Nn];
        q4 += 2; bl += 4 * Nn; cl += 4 * Nn;
        h = EXP2F(a.x * AnE) * h + a.y * B0;  pS[s][half * 4 + 0][n] = h * C0;
        h = EXP2F(a.z * AnE) * h + a.w * B1;  pS[s][half * 4 + 1][n] = h * C1;
        h = EXP2F(bq.x * AnE) * h + bq.y * B2; pS[s][half * 4 + 2][n] = h * C2;
        h = EXP2F(bq.z * AnE) * h + bq.w * B3; pS[s][half * 4 + 3][n] = h * C3;
        sumD += (a.x + a.z) + (bq.x + bq.z);
        cmx = fmaxf(cmx, fmaxf(fmaxf(fabsf(C0), fabsf(C1)),
                               fmaxf(fabsf(C2), fabsf(C3))));
      }
      // reduce the 8-step tile: lane sums a quarter-row, 2 shuffles combine
      const float4 a4 = *(const float4*)&pS[s][rrow][qtr * 8];
      const float4 d4v = *(const float4*)&pS[s][rrow][qtr * 8 + 4];
      float sum = ((a4.x + a4.y) + (a4.z + a4.w)) + ((d4v.x + d4v.y) + (d4v.z + d4v.w));
      sum += __shfl_xor(sum, 8);
      sum += __shfl_xor(sum, 16);
      if (n < 8) yP[t8 * 8 + n] = sum;
    }
  }
  hendS[s][n] = h;
  const float cmxAll = hmax32(cmx);
  if (n == 0) { sumDS[s] = sumD; cmaxS[s] = cmxAll; }
  __syncthreads();
  // ---- exact serial carry combine over 16 chunks (half-wave) ----
  if (tid < 32) {
    float carry = 0.f;
    #pragma unroll
    for (int s2 = 0; s2 < 16; ++s2) {
      carryS[s2][tid] = carry;
      carry = EXP2F(AnE * sumDS[s2]) * carry + hendS[s2][tid];
    }
  }
  __syncthreads();
  // ---- truncated carry correction, tiled like pass 1 ----
  const float carry = carryS[s][n];
  const float mc = hmax32(fabsf(carry));
  const float AmaxE = hmax32(AnE);               // all < 0; max = slowest decay
  // smallest P with 32*mc*cmax*2^(AmaxE*P) <= 1e-5  (log2f(0) = -inf => skip)
  const float Pstop = log2f(mc * cmaxS[s] * 3.2e6f) / (-AmaxE);
  {
    float hc = carry, P = 0.f;
    const float4* q4 = (const float4*)(dP + lbeg);
    const float* cl = cP + (size_t)lbeg * Nn;
    for (int t8 = 0; t8 < LCc / 8; ++t8) {
      if (!(P < Pstop)) break;                   // uniform per half-wave
      #pragma unroll
      for (int half = 0; half < 2; ++half) {
        const float4 qa = q4[0], qb = q4[1];
        q4 += 2;
        hc *= EXP2F(qa.x * AnE); pS[s][half * 4 + 0][n] = hc * cl[0];
        hc *= EXP2F(qa.z * AnE); pS[s][half * 4 + 1][n] = hc * cl[Nn];
        hc *= EXP2F(qb.x * AnE); pS[s][half * 4 + 2][n] = hc * cl[2 * Nn];
        hc *= EXP2F(qb.z * AnE); pS[s][half * 4 + 3][n] = hc * cl[3 * Nn];
        P += (qa.x + qa.z) + (qb.x + qb.z);
        cl += 4 * Nn;
      }
      const float4 a4 = *(const float4*)&pS[s][rrow][qtr * 8];
      const float4 d4v = *(const float4*)&pS[s][rrow][qtr * 8 + 4];
      float sum = ((a4.x + a4.y) + (a4.z + a4.w)) + ((d4v.x + d4v.y) + (d4v.z + d4v.w));
      sum += __shfl_xor(sum, 8);
      sum += __shfl_xor(sum, 16);
      if (n < 8) yP[t8 * 8 + n] += sum;
    }
  }
}

// ---------------- K5: merge + Ds-term + out-LN + SiLU(z)* + out_proj + residual ----------------
// Block = one 4x4 pixel tile: ALL four scan directions stage as float4 loads
// (dir0/2 contiguous along w, dir1/3 contiguous along h).
__global__ __launch_bounds__(256) void k5_merge(
    const float* __restrict__ ys, const float* __restrict__ zb,
    const float* __restrict__ og, const float* __restrict__ ob,
    const float* __restrict__ Wo, const float* __restrict__ resid,
    const float* __restrict__ xc, const float* __restrict__ DsP,
    float* __restrict__ out)
{
  __shared__ float ysS[4][16][128];
  __shared__ float tS[16][128];
  __shared__ float oS[64][17];
  __shared__ float xcS[16][128];
  const int tid = threadIdx.x;
  const int wv = tid >> 6, lane = tid & 63;
  const int tb = blockIdx.x;           // 288 tiles = 2 b x 12 x 12
  const int b = tb / 144;
  const int ti = tb % 144;
  const int tr = ti / 12, tc = ti % 12;
  const int h0 = tr * 4, w0 = tc * 4;
  {  // stage xc + 4 direction tiles; p = i*4+j (i = row in tile, j = col)
    const int dch = tid & 127, half = tid >> 7;   // 2 threads per channel
    #pragma unroll
    for (int ii = 0; ii < 2; ++ii) {
      const int i = half * 2 + ii;
      const int l0 = (h0 + i) * Ww + w0;
      float4 v;
      v = *(const float4*)&xc[(b * Dd + dch) * Ll + l0];
      xcS[i * 4 + 0][dch] = v.x; xcS[i * 4 + 1][dch] = v.y;
      xcS[i * 4 + 2][dch] = v.z; xcS[i * 4 + 3][dch] = v.w;
      v = *(const float4*)&ys[((size_t)(b * Kk + 0) * Dd + dch) * Ll + l0];
      ysS[0][i * 4 + 0][dch] = v.x; ysS[0][i * 4 + 1][dch] = v.y;
      ysS[0][i * 4 + 2][dch] = v.z; ysS[0][i * 4 + 3][dch] = v.w;
      const int r2 = Ll - 4 - (h0 + i) * Ww - w0;   // dir2: l = Ll-1-l0, reversed
      v = *(const float4*)&ys[((size_t)(b * Kk + 2) * Dd + dch) * Ll + r2];
      ysS[2][i * 4 + 3][dch] = v.x; ysS[2][i * 4 + 2][dch] = v.y;
      ysS[2][i * 4 + 1][dch] = v.z; ysS[2][i * 4 + 0][dch] = v.w;
    }
    #pragma unroll
    for (int jj = 0; jj < 2; ++jj) {
      const int j = half * 2 + jj;
      const int l1 = (w0 + j) * Hh + h0;            // dir1: col-major, i contiguous
      float4 v = *(const float4*)&ys[((size_t)(b * Kk + 1) * Dd + dch) * Ll + l1];
      ysS[1][0 * 4 + j][dch] = v.x; ysS[1][1 * 4 + j][dch] = v.y;
      ysS[1][2 * 4 + j][dch] = v.z; ysS[1][3 * 4 + j][dch] = v.w;
      const int r3 = Ll - 4 - (w0 + j) * Hh - h0;   // dir3: l = Ll-1-l1, reversed
      v = *(const float4*)&ys[((size_t)(b * Kk + 3) * Dd + dch) * Ll + r3];
      ysS[3][3 * 4 + j][dch] = v.x; ysS[3][2 * 4 + j][dch] = v.y;
      ysS[3][1 * 4 + j][dch] = v.z; ysS[3][0 * 4 + j][dch] = v.w;
    }
  }
  float sDs[2];
  #pragma unroll
  for (int m = 0; m < 2; ++m) {
    const int dch = lane + 64 * m;
    sDs[m] = DsP[dch] + DsP[Dd + dch] + DsP[2 * Dd + dch] + DsP[3 * Dd + dch];
  }
  __syncthreads();
  for (int pi = 0; pi < 4; ++pi) {
    const int p = wv * 4 + pi;
    const int l0 = (h0 + (p >> 2)) * Ww + w0 + (p & 3);
    float tv[2];
    #pragma unroll
    for (int m = 0; m < 2; ++m) {
      const int dch = lane + 64 * m;
      tv[m] = ysS[0][p][dch] + ysS[1][p][dch] + ysS[2][p][dch] + ysS[3][p][dch]
            + sDs[m] * xcS[p][dch];
    }
    const float mu = wsum64(tv[0] + tv[1]) * (1.0f / 128.0f);
    const float q = wsum64((tv[0] - mu) * (tv[0] - mu) +
                           (tv[1] - mu) * (tv[1] - mu)) * (1.0f / 128.0f);
    const float rs = rsqrtf(q + EPSf);
    #pragma unroll
    for (int m = 0; m < 2; ++m) {
      const int dch = lane + 64 * m;
      const float zz = zb[(size_t)(b * Ll + l0) * Dd + dch];
      const float sig = 1.0f / (1.0f + __expf(-zz));
      tS[p][dch] = ((tv[m] - mu) * rs * og[dch] + ob[dch]) * (zz * sig);
    }
  }
  __syncthreads();
  float acc[4] = {0.f, 0.f, 0.f, 0.f};
  const float4* W4 = (const float4*)Wo;     // out_proj_w (64,128)
  for (int d4 = 0; d4 < 32; ++d4) {
    const float4 w4 = W4[lane * 32 + d4];
    #pragma unroll
    for (int pi = 0; pi < 4; ++pi) {
      const float4 t4 = ((const float4*)tS[wv * 4 + pi])[d4];
      acc[pi] += t4.x * w4.x + t4.y * w4.y + t4.z * w4.z + t4.w * w4.w;
    }
  }
  #pragma unroll
  for (int pi = 0; pi < 4; ++pi) oS[lane][wv * 4 + pi] = acc[pi];
  __syncthreads();
  const int c = tid >> 2, q = tid & 3;     // c = out channel, q = tile row
  const size_t obase = (size_t)(b * Cc + c) * Ll + (size_t)(h0 + q) * Ww + w0;
  const float4 r4 = *(const float4*)(resid + obase);
  float4 o4;
  o4.x = oS[c][q * 4 + 0] + r4.x;
  o4.y = oS[c][q * 4 + 1] + r4.y;
  o4.z = oS[c][q * 4 + 2] + r4.z;
  o4.w = oS[c][q * 4 + 3] + r4.w;
  *(float4*)(out + obase) = o4;
}

extern "C" void kernel_launch(void* const* d_in, const int* in_sizes, int n_in,
                              void* d_out, int out_size, void* d_ws, size_t ws_size,
                              hipStream_t stream)
{
  (void)in_sizes; (void)n_in; (void)out_size; (void)ws_size;
  const float* fufea1     = (const float*)d_in[0];
  const float* ln_g       = (const float*)d_in[1];
  const float* ln_b       = (const float*)d_in[2];
  const float* in_proj_w  = (const float*)d_in[3];
  const float* conv_w     = (const float*)d_in[4];
  const float* conv_b     = (const float*)d_in[5];
  const float* x_proj_w   = (const float*)d_in[6];
  const float* dt_w       = (const float*)d_in[7];
  const float* dt_b       = (const float*)d_in[8];
  const float* A_logs     = (const float*)d_in[9];
  const float* Ds         = (const float*)d_in[10];
  const float* out_ln_g   = (const float*)d_in[11];
  const float* out_ln_b   = (const float*)d_in[12];
  const float* out_proj_w = (const float*)d_in[13];

  float* ws = (float*)d_ws;
  // k4's 2-deep prefetch overreads <=1KB past dd2/Bm/Cm row ends -> keep a live
  // buffer after each of them (dd2 -> Bm -> Cm -> zb; loads only).
  float2* dd2 = (float2*)ws;        // (B,K,D,L) float2  4718592 floats
  float* Bm   = ws + 4718592;       // (B,K,L,N)          589824
  float* Cm   = ws + 5308416;       // (B,K,L,N)          589824
  float* zb   = ws + 5898240;       // (B,L,D)            589824
  float* xc   = ws + 6488064;       // (B,D,L)            589824
  float* ysb  = ws + 7077888;       // (B,K,D,L)         2359296
  float* xin  = ws + 7077888;       // (B,D,L) — overlaps ysb (dead before k4)
  // total: 9437184 floats = 37.75 MB

  k1_ln_inproj<<<288, 256, 0, stream>>>(fufea1, ln_g, ln_b, in_proj_w, xin, zb);
  k3_proj<<<576, 512, 0, stream>>>(xin, conv_w, conv_b, x_proj_w, dt_w, dt_b,
                                   xc, dd2, Bm, Cm);
  k4_scan<<<1024, 512, 0, stream>>>(dd2, Bm, Cm, A_logs, ysb);
  k5_merge<<<288, 256, 0, stream>>>(ysb, zb, out_ln_g, out_ln_b, out_proj_w, fufea1,
                                    xc, Ds, (float*)d_out);
}

// Round 5
// 201.050 us; speedup vs baseline: 1.1150x; 1.0344x over previous
//
#include <hip/hip_runtime.h>

#define Cc 64
#define Dd 128
#define Nn 32
#define Kk 4
#define Rr 4
#define Bb 2
#define Hh 48
#define Ww 48
#define Ll 2304
#define EPSf 1e-5f
#define LCc 144   // scan chunk length = L/16

#if __has_builtin(__builtin_amdgcn_exp2f)
#define EXP2F __builtin_amdgcn_exp2f
#else
#define EXP2F exp2f
#endif

__device__ __forceinline__ float wsum64(float v) {
  v += __shfl_xor(v, 32);
  v += __shfl_xor(v, 16);
  v += __shfl_xor(v, 8);
  v += __shfl_xor(v, 4);
  v += __shfl_xor(v, 2);
  v += __shfl_xor(v, 1);
  return v;
}

// max over the 32 lanes of a half-wave (masks stay within the half)
__device__ __forceinline__ float hmax32(float v) {
  v = fmaxf(v, __shfl_xor(v, 1));
  v = fmaxf(v, __shfl_xor(v, 2));
  v = fmaxf(v, __shfl_xor(v, 4));
  v = fmaxf(v, __shfl_xor(v, 8));
  v = fmaxf(v, __shfl_xor(v, 16));
  return v;
}

// ---------------- K1: pre-LN (over C) + in_proj (C -> 2D), split x/z ----------------
// xin now PIXEL-MAJOR (b,l,d): written exactly like zb (coalesced 256B/instr),
// which deletes the old xaS LDS roundtrip + final phase entirely.
__global__ __launch_bounds__(256) void k1_ln_inproj(
    const float* __restrict__ x, const float* __restrict__ g,
    const float* __restrict__ bta, const float* __restrict__ Wp,
    float* __restrict__ xin, float* __restrict__ zb)
{
  __shared__ float xS[16][65];
  __shared__ float xnS[16][64];
  const int tid = threadIdx.x;
  const int wv = tid >> 6, lane = tid & 63;
  const int pbase = blockIdx.x * 16;       // 4608 pixels total, no b-straddle
  const int b = pbase / Ll;
  const int lbase = pbase % Ll;
  {  // coalesced staging: thread -> (c, 4 consecutive l)
    const int c = tid >> 2, li0 = (tid & 3) * 4;
    const float4 v4 = *(const float4*)&x[(b * Cc + c) * Ll + lbase + li0];
    xS[li0 + 0][c] = v4.x;
    xS[li0 + 1][c] = v4.y;
    xS[li0 + 2][c] = v4.z;
    xS[li0 + 3][c] = v4.w;
  }
  __syncthreads();
  const float gv = g[lane], bv = bta[lane];
  for (int pi = 0; pi < 4; ++pi) {
    const int p = wv * 4 + pi;
    const float v = xS[p][lane];
    const float mu = wsum64(v) * (1.0f / 64.0f);
    const float dv = v - mu;
    const float var = wsum64(dv * dv) * (1.0f / 64.0f);
    const float rs = rsqrtf(var + EPSf);
    xnS[p][lane] = dv * rs * gv + bv;
  }
  __syncthreads();
  float acc[4][4];
  #pragma unroll
  for (int pi = 0; pi < 4; ++pi)
    #pragma unroll
    for (int m = 0; m < 4; ++m) acc[pi][m] = 0.f;
  const float4* W4 = (const float4*)Wp;
  #pragma unroll 4
  for (int c4 = 0; c4 < 16; ++c4) {
    float4 xn4[4];
    #pragma unroll
    for (int pi = 0; pi < 4; ++pi)
      xn4[pi] = ((const float4*)xnS[wv * 4 + pi])[c4];
    #pragma unroll
    for (int m = 0; m < 4; ++m) {
      const float4 w4 = W4[(lane + 64 * m) * 16 + c4];
      #pragma unroll
      for (int pi = 0; pi < 4; ++pi)
        acc[pi][m] += xn4[pi].x * w4.x + xn4[pi].y * w4.y +
                      xn4[pi].z * w4.z + xn4[pi].w * w4.w;
    }
  }
  #pragma unroll
  for (int pi = 0; pi < 4; ++pi) {
    const int l = lbase + wv * 4 + pi;
    const size_t base = (size_t)(b * Ll + l) * Dd;
    xin[base + lane]      = acc[pi][0];
    xin[base + lane + 64] = acc[pi][1];
    zb[base + lane]       = acc[pi][2];
    zb[base + lane + 64]  = acc[pi][3];
  }
}

// ---------------- K3: conv3x3+SiLU (fused) + projections -> xc, {delta,delta*u}, B, C ----------------
// xin/xc pixel-major (b,l,d): staging loads and xc writes fully coalesced.
// Bm/Cm in the COALESCED (b,k,l,n) layout (measured best: r2 = 53.9us k4).
__global__ __launch_bounds__(512) void k3_proj(
    const float* __restrict__ xin, const float* __restrict__ cw,
    const float* __restrict__ cb, const float* __restrict__ xpw,
    const float* __restrict__ dtw, const float* __restrict__ dtb,
    float* __restrict__ xc, float2* __restrict__ dd2,
    float* __restrict__ Bm, float* __restrict__ Cm)
{
  __shared__ float xinS[128][31];   // odd stride -> conflict-free
  __shared__ float xvS[8][132];
  __shared__ float dtsS[8][16];
  const int t = threadIdx.x;
  const int pb = blockIdx.x * 8;
  const int b = pb / Ll;
  const int lb = pb % Ll;
  const int h0 = lb / Ww, w0 = lb % Ww;
  // stage 3 rows x 10 cols x 128 d of xin (pixel-major), zero-padded at borders;
  // d-fastest -> 512B contiguous per (hh,ww)
  for (int i = t; i < 3840; i += 512) {
    const int d = i & 127, j = i >> 7;
    const int r = j / 10, c = j % 10;
    const int hh = h0 + r - 1, ww = w0 + c - 1;
    float v = 0.f;
    if (hh >= 0 && hh < Hh && ww >= 0 && ww < Ww)
      v = xin[((size_t)(b * Ll) + hh * Ww + ww) * Dd + d];
    xinS[d][j] = v;
  }
  __syncthreads();
  // depthwise conv + bias + SiLU -> xvS (pixel-major for the GEMM below)
  for (int i = t; i < 1024; i += 512) {
    const int pi = i >> 7, d = i & 127;
    float acc = cb[d];
    #pragma unroll
    for (int r = 0; r < 3; ++r)
      #pragma unroll
      for (int c = 0; c < 3; ++c)
        acc += xinS[d][r * 10 + pi + c] * cw[d * 9 + r * 3 + c];
    const float sig = 1.0f / (1.0f + __expf(-acc));
    xvS[pi][d] = acc * sig;
  }
  __syncthreads();
  if (t < 272) {   // projection GEMM: 4 k x 68 c rows, 8 px each
    const int k = t / 68, c = t % 68;
    const size_t bkL = (size_t)(b * Kk + k) * Ll;
    float acc[8];
    #pragma unroll
    for (int pi = 0; pi < 8; ++pi) acc[pi] = 0.f;
    const float4* w4p = (const float4*)(xpw + (k * 68 + c) * 128);
    for (int d4 = 0; d4 < 32; ++d4) {
      const float4 w4 = w4p[d4];
      #pragma unroll
      for (int pi = 0; pi < 8; ++pi) {
        const float4 x4 = ((const float4*)xvS[pi])[d4];
        acc[pi] += x4.x * w4.x + x4.y * w4.y + x4.z * w4.z + x4.w * w4.w;
      }
    }
    #pragma unroll
    for (int pi = 0; pi < 8; ++pi) {
      const int l0 = lb + pi;
      const int h = l0 / Ww, w = l0 % Ww;
      int lk;
      if      (k == 0) lk = l0;
      else if (k == 1) lk = w * Hh + h;
      else if (k == 2) lk = Ll - 1 - l0;
      else             lk = Ll - 1 - (w * Hh + h);
      if (c < Rr)            dtsS[pi][k * 4 + c] = acc[pi];
      else if (c < Rr + Nn)  Bm[(bkL + lk) * Nn + (c - Rr)] = acc[pi];
      else                   Cm[(bkL + lk) * Nn + (c - Rr - Nn)] = acc[pi];
    }
  } else {   // idle-during-proj threads handle the xc write (pixel-major, coalesced)
    for (int i = t - 272; i < 1024; i += 240) {
      const int pi = i >> 7, d = i & 127;
      xc[((size_t)(b * Ll) + lb + pi) * Dd + d] = xvS[pi][d];
    }
  }
  __syncthreads();
  {  // delta + softplus + pack {delta, delta*u}
    const int k = t >> 7, dd = t & 127;
    const float4 dw = *(const float4*)&dtw[(k * Dd + dd) * 4];
    const float biasv = dtb[k * Dd + dd];
    float2* drow = dd2 + ((size_t)((b * Kk + k) * Dd) + dd) * Ll;
    float2 buf[8];
    #pragma unroll
    for (int pi = 0; pi < 8; ++pi) {
      const float a = biasv
          + dtsS[pi][k * 4 + 0] * dw.x + dtsS[pi][k * 4 + 1] * dw.y
          + dtsS[pi][k * 4 + 2] * dw.z + dtsS[pi][k * 4 + 3] * dw.w;
      const float sp = (a > 20.f) ? a : log1pf(__expf(a));
      buf[pi] = make_float2(sp, sp * xvS[pi][dd]);
    }
    if (k == 0) {
      float4* f4 = (float4*)(drow + lb);
      #pragma unroll
      for (int j = 0; j < 4; ++j)
        f4[j] = make_float4(buf[2 * j].x, buf[2 * j].y, buf[2 * j + 1].x, buf[2 * j + 1].y);
    } else if (k == 2) {
      float4* f4 = (float4*)(drow + (Ll - 8 - lb));
      #pragma unroll
      for (int j = 0; j < 4; ++j)
        f4[j] = make_float4(buf[7 - 2 * j].x, buf[7 - 2 * j].y, buf[6 - 2 * j].x, buf[6 - 2 * j].y);
    } else {
      #pragma unroll
      for (int pi = 0; pi < 8; ++pi) {
        const int l0 = lb + pi;
        const int h = l0 / Ww, w = l0 % Ww;
        int lk = w * Hh + h;
        if (k == 3) lk = Ll - 1 - lk;
        drow[lk] = buf[pi];
      }
    }
  }
}

// ---------------- K4: single-pass scan + TILED truncated carry correction ----------------
// EXACT r2 structure (measured 53.9us optimum). Pass 1: local scan (carry=0) writes
// y_local, records hend/sumD/max|c|. Serial combine gives exact carries. Correction adds
//   y_t += sum_n carry_n * exp(A_n * P_t) * c_t[n]
// tiled like pass 1, stopping at tile granularity once the rigorous bound
// 32*max|carry|*max|c|*2^(AmaxE*P) < 1e-5 holds (P = in-chunk delta prefix, >0).
// block index = (d<<3)|(b*4+k): %8 XCD round-robin keeps one (b,k)'s B/C/dd2 slice
// L2-resident per XCD.
__global__ __launch_bounds__(512) void k4_scan(
    const float2* __restrict__ dd2, const float* __restrict__ Bm,
    const float* __restrict__ Cm, const float* __restrict__ Alogs,
    float* __restrict__ ys)
{
  __shared__ float hendS[16][32];
  __shared__ float carryS[16][32];
  __shared__ float sumDS[16];
  __shared__ float cmaxS[16];
  __shared__ float pS[16][8][36];
  const int tid = threadIdx.x;
  const int s = tid >> 5, n = tid & 31;
  const int blk = blockIdx.x;
  const int bk = blk & 7;          // (b,k) -> XCD
  const int d = blk >> 3;
  const int b = bk >> 2, k = bk & 3;
  const float An = -__expf(Alogs[(k * Dd + d) * Nn + n]);
  const float AnE = An * 1.44269504f;
  const size_t bkL = (size_t)(b * Kk + k) * Ll;
  const float2* dP = dd2 + ((size_t)((b * Kk + k) * Dd) + d) * Ll;
  const float* bP = Bm + bkL * Nn + n;
  const float* cP = Cm + bkL * Nn + n;
  const int lbeg = s * LCc;
  float* yP = ys + ((size_t)((b * Kk + k) * Dd) + d) * Ll + lbeg;
  const int rrow = n & 7, qtr = n >> 3;

  // ---- pass 1: local scan (carry=0), y_local out, hend + sumD + chunk max|c| ----
  float h = 0.f, sumD = 0.f, cmx = 0.f;
  {
    const float4* q4 = (const float4*)(dP + lbeg);
    const float* bl = bP + (size_t)lbeg * Nn;
    const float* cl = cP + (size_t)lbeg * Nn;
    float4 qa = q4[0], qb = q4[1];
    float b0 = bl[0], b1 = bl[Nn], b2 = bl[2 * Nn], b3 = bl[3 * Nn];
    float c0 = cl[0], c1 = cl[Nn], c2 = cl[2 * Nn], c3 = cl[3 * Nn];
    for (int t8 = 0; t8 < LCc / 8; ++t8) {
      #pragma unroll
      for (int half = 0; half < 2; ++half) {
        q4 += 2; bl += 4 * Nn; cl += 4 * Nn;   // prefetch next (overread guarded by ws layout)
        const float4 qa_n = q4[0], qb_n = q4[1];
        const float b0n = bl[0], b1n = bl[Nn], b2n = bl[2 * Nn], b3n = bl[3 * Nn];
        const float c0n = cl[0], c1n = cl[Nn], c2n = cl[2 * Nn], c3n = cl[3 * Nn];
        h = EXP2F(qa.x * AnE) * h + qa.y * b0; pS[s][half * 4 + 0][n] = h * c0;
        h = EXP2F(qa.z * AnE) * h + qa.w * b1; pS[s][half * 4 + 1][n] = h * c1;
        h = EXP2F(qb.x * AnE) * h + qb.y * b2; pS[s][half * 4 + 2][n] = h * c2;
        h = EXP2F(qb.z * AnE) * h + qb.w * b3; pS[s][half * 4 + 3][n] = h * c3;
        sumD += (qa.x + qa.z) + (qb.x + qb.z);
        cmx = fmaxf(cmx, fmaxf(fmaxf(fabsf(c0), fabsf(c1)),
                               fmaxf(fabsf(c2), fabsf(c3))));
        qa = qa_n; qb = qb_n; b0 = b0n; b1 = b1n; b2 = b2n; b3 = b3n;
        c0 = c0n; c1 = c1n; c2 = c2n; c3 = c3n;
      }
      // reduce the 8-step tile: lane sums a quarter-row, 2 shuffles combine
      const float4 a4 = *(const float4*)&pS[s][rrow][qtr * 8];
      const float4 d4v = *(const float4*)&pS[s][rrow][qtr * 8 + 4];
      float sum = ((a4.x + a4.y) + (a4.z + a4.w)) + ((d4v.x + d4v.y) + (d4v.z + d4v.w));
      sum += __shfl_xor(sum, 8);
      sum += __shfl_xor(sum, 16);
      if (n < 8) yP[t8 * 8 + n] = sum;
    }
  }
  hendS[s][n] = h;
  const float cmxAll = hmax32(cmx);
  if (n == 0) { sumDS[s] = sumD; cmaxS[s] = cmxAll; }
  __syncthreads();
  // ---- exact serial carry combine over 16 chunks (half-wave) ----
  if (tid < 32) {
    float carry = 0.f;
    #pragma unroll
    for (int s2 = 0; s2 < 16; ++s2) {
      carryS[s2][tid] = carry;
      carry = EXP2F(AnE * sumDS[s2]) * carry + hendS[s2][tid];
    }
  }
  __syncthreads();
  // ---- truncated carry correction, tiled like pass 1 ----
  const float carry = carryS[s][n];
  const float mc = hmax32(fabsf(carry));
  const float AmaxE = hmax32(AnE);               // all < 0; max = slowest decay
  // smallest P with 32*mc*cmax*2^(AmaxE*P) <= 1e-5  (log2f(0) = -inf => skip)
  const float Pstop = log2f(mc * cmaxS[s] * 3.2e6f) / (-AmaxE);
  {
    float hc = carry, P = 0.f;
    const float4* q4 = (const float4*)(dP + lbeg);
    const float* cl = cP + (size_t)lbeg * Nn;
    for (int t8 = 0; t8 < LCc / 8; ++t8) {
      if (!(P < Pstop)) break;                   // uniform per half-wave
      #pragma unroll
      for (int half = 0; half < 2; ++half) {
        const float4 qa = q4[0], qb = q4[1];
        q4 += 2;
        hc *= EXP2F(qa.x * AnE); pS[s][half * 4 + 0][n] = hc * cl[0];
        hc *= EXP2F(qa.z * AnE); pS[s][half * 4 + 1][n] = hc * cl[Nn];
        hc *= EXP2F(qb.x * AnE); pS[s][half * 4 + 2][n] = hc * cl[2 * Nn];
        hc *= EXP2F(qb.z * AnE); pS[s][half * 4 + 3][n] = hc * cl[3 * Nn];
        P += (qa.x + qa.z) + (qb.x + qb.z);
        cl += 4 * Nn;
      }
      const float4 a4 = *(const float4*)&pS[s][rrow][qtr * 8];
      const float4 d4v = *(const float4*)&pS[s][rrow][qtr * 8 + 4];
      float sum = ((a4.x + a4.y) + (a4.z + a4.w)) + ((d4v.x + d4v.y) + (d4v.z + d4v.w));
      sum += __shfl_xor(sum, 8);
      sum += __shfl_xor(sum, 16);
      if (n < 8) yP[t8 * 8 + n] += sum;
    }
  }
}

// ---------------- K5: merge + Ds-term + out-LN + SiLU(z)* + out_proj + residual ----------------
// Block = one 4x4 pixel tile: ALL four scan directions stage as float4 loads
// (dir0/2 contiguous along w, dir1/3 contiguous along h); xc pixel-major -> coalesced.
__global__ __launch_bounds__(256) void k5_merge(
    const float* __restrict__ ys, const float* __restrict__ zb,
    const float* __restrict__ og, const float* __restrict__ ob,
    const float* __restrict__ Wo, const float* __restrict__ resid,
    const float* __restrict__ xc, const float* __restrict__ DsP,
    float* __restrict__ out)
{
  __shared__ float ysS[4][16][128];
  __shared__ float tS[16][128];
  __shared__ float oS[64][17];
  __shared__ float xcS[16][128];
  const int tid = threadIdx.x;
  const int wv = tid >> 6, lane = tid & 63;
  const int tb = blockIdx.x;           // 288 tiles = 2 b x 12 x 12
  const int b = tb / 144;
  const int ti = tb % 144;
  const int tr = ti / 12, tc = ti % 12;
  const int h0 = tr * 4, w0 = tc * 4;
  {  // stage xc (pixel-major, float4 along d, fully coalesced)
    const int p = tid >> 4, qq = tid & 15;
    const int l0 = (h0 + (p >> 2)) * Ww + w0 + (p & 3);
    const float4* src = (const float4*)&xc[((size_t)(b * Ll) + l0) * Dd];
    ((float4*)xcS[p])[qq]      = src[qq];
    ((float4*)xcS[p])[qq + 16] = src[qq + 16];
  }
  {  // stage 4 direction tiles; p = i*4+j (i = row in tile, j = col)
    const int dch = tid & 127, half = tid >> 7;   // 2 threads per channel
    #pragma unroll
    for (int ii = 0; ii < 2; ++ii) {
      const int i = half * 2 + ii;
      const int l0 = (h0 + i) * Ww + w0;
      float4 v;
      v = *(const float4*)&ys[((size_t)(b * Kk + 0) * Dd + dch) * Ll + l0];
      ysS[0][i * 4 + 0][dch] = v.x; ysS[0][i * 4 + 1][dch] = v.y;
      ysS[0][i * 4 + 2][dch] = v.z; ysS[0][i * 4 + 3][dch] = v.w;
      const int r2 = Ll - 4 - (h0 + i) * Ww - w0;   // dir2: l = Ll-1-l0, reversed
      v = *(const float4*)&ys[((size_t)(b * Kk + 2) * Dd + dch) * Ll + r2];
      ysS[2][i * 4 + 3][dch] = v.x; ysS[2][i * 4 + 2][dch] = v.y;
      ysS[2][i * 4 + 1][dch] = v.z; ysS[2][i * 4 + 0][dch] = v.w;
    }
    #pragma unroll
    for (int jj = 0; jj < 2; ++jj) {
      const int j = half * 2 + jj;
      const int l1 = (w0 + j) * Hh + h0;            // dir1: col-major, i contiguous
      float4 v = *(const float4*)&ys[((size_t)(b * Kk + 1) * Dd + dch) * Ll + l1];
      ysS[1][0 * 4 + j][dch] = v.x; ysS[1][1 * 4 + j][dch] = v.y;
      ysS[1][2 * 4 + j][dch] = v.z; ysS[1][3 * 4 + j][dch] = v.w;
      const int r3 = Ll - 4 - (w0 + j) * Hh - h0;   // dir3: l = Ll-1-l1, reversed
      v = *(const float4*)&ys[((size_t)(b * Kk + 3) * Dd + dch) * Ll + r3];
      ysS[3][3 * 4 + j][dch] = v.x; ysS[3][2 * 4 + j][dch] = v.y;
      ysS[3][1 * 4 + j][dch] = v.z; ysS[3][0 * 4 + j][dch] = v.w;
    }
  }
  float sDs[2];
  #pragma unroll
  for (int m = 0; m < 2; ++m) {
    const int dch = lane + 64 * m;
    sDs[m] = DsP[dch] + DsP[Dd + dch] + DsP[2 * Dd + dch] + DsP[3 * Dd + dch];
  }
  __syncthreads();
  for (int pi = 0; pi < 4; ++pi) {
    const int p = wv * 4 + pi;
    const int l0 = (h0 + (p >> 2)) * Ww + w0 + (p & 3);
    float tv[2];
    #pragma unroll
    for (int m = 0; m < 2; ++m) {
      const int dch = lane + 64 * m;
      tv[m] = ysS[0][p][dch] + ysS[1][p][dch] + ysS[2][p][dch] + ysS[3][p][dch]
            + sDs[m] * xcS[p][dch];
    }
    const float mu = wsum64(tv[0] + tv[1]) * (1.0f / 128.0f);
    const float q = wsum64((tv[0] - mu) * (tv[0] - mu) +
                           (tv[1] - mu) * (tv[1] - mu)) * (1.0f / 128.0f);
    const float rs = rsqrtf(q + EPSf);
    #pragma unroll
    for (int m = 0; m < 2; ++m) {
      const int dch = lane + 64 * m;
      const float zz = zb[(size_t)(b * Ll + l0) * Dd + dch];
      const float sig = 1.0f / (1.0f + __expf(-zz));
      tS[p][dch] = ((tv[m] - mu) * rs * og[dch] + ob[dch]) * (zz * sig);
    }
  }
  __syncthreads();
  float acc[4] = {0.f, 0.f, 0.f, 0.f};
  const float4* W4 = (const float4*)Wo;     // out_proj_w (64,128)
  for (int d4 = 0; d4 < 32; ++d4) {
    const float4 w4 = W4[lane * 32 + d4];
    #pragma unroll
    for (int pi = 0; pi < 4; ++pi) {
      const float4 t4 = ((const float4*)tS[wv * 4 + pi])[d4];
      acc[pi] += t4.x * w4.x + t4.y * w4.y + t4.z * w4.z + t4.w * w4.w;
    }
  }
  #pragma unroll
  for (int pi = 0; pi < 4; ++pi) oS[lane][wv * 4 + pi] = acc[pi];
  __syncthreads();
  const int c = tid >> 2, q = tid & 3;     // c = out channel, q = tile row
  const size_t obase = (size_t)(b * Cc + c) * Ll + (size_t)(h0 + q) * Ww + w0;
  const float4 r4 = *(const float4*)(resid + obase);
  float4 o4;
  o4.x = oS[c][q * 4 + 0] + r4.x;
  o4.y = oS[c][q * 4 + 1] + r4.y;
  o4.z = oS[c][q * 4 + 2] + r4.z;
  o4.w = oS[c][q * 4 + 3] + r4.w;
  *(float4*)(out + obase) = o4;
}

extern "C" void kernel_launch(void* const* d_in, const int* in_sizes, int n_in,
                              void* d_out, int out_size, void* d_ws, size_t ws_size,
                              hipStream_t stream)
{
  (void)in_sizes; (void)n_in; (void)out_size; (void)ws_size;
  const float* fufea1     = (const float*)d_in[0];
  const float* ln_g       = (const float*)d_in[1];
  const float* ln_b       = (const float*)d_in[2];
  const float* in_proj_w  = (const float*)d_in[3];
  const float* conv_w     = (const float*)d_in[4];
  const float* conv_b     = (const float*)d_in[5];
  const float* x_proj_w   = (const float*)d_in[6];
  const float* dt_w       = (const float*)d_in[7];
  const float* dt_b       = (const float*)d_in[8];
  const float* A_logs     = (const float*)d_in[9];
  const float* Ds         = (const float*)d_in[10];
  const float* out_ln_g   = (const float*)d_in[11];
  const float* out_ln_b   = (const float*)d_in[12];
  const float* out_proj_w = (const float*)d_in[13];

  float* ws = (float*)d_ws;
  // k4's 1-deep prefetch overreads a few hundred bytes past dd2/Bm/Cm row
  // ends -> keep a live buffer after each of them (dd2 -> Bm -> Cm -> zb).
  float2* dd2 = (float2*)ws;        // (B,K,D,L) float2  4718592 floats
  float* Bm   = ws + 4718592;       // (B,K,L,N)          589824
  float* Cm   = ws + 5308416;       // (B,K,L,N)          589824
  float* zb   = ws + 5898240;       // (B,L,D)            589824
  float* xc   = ws + 6488064;       // (B,L,D) pixel-major 589824
  float* ysb  = ws + 7077888;       // (B,K,D,L)         2359296
  float* xin  = ws + 7077888;       // (B,L,D) pixel-major — overlaps ysb (dead before k4)
  // total: 9437184 floats = 37.75 MB

  k1_ln_inproj<<<288, 256, 0, stream>>>(fufea1, ln_g, ln_b, in_proj_w, xin, zb);
  k3_proj<<<576, 512, 0, stream>>>(xin, conv_w, conv_b, x_proj_w, dt_w, dt_b,
                                   xc, dd2, Bm, Cm);
  k4_scan<<<1024, 512, 0, stream>>>(dd2, Bm, Cm, A_logs, ysb);
  k5_merge<<<288, 256, 0, stream>>>(ysb, zb, out_ln_g, out_ln_b, out_proj_w, fufea1,
                                    xc, Ds, (float*)d_out);
}